// Round 14
// baseline (329.416 us; speedup 1.0000x reference)
//
#include <hip/hip_runtime.h>
#include <hip/hip_bf16.h>
#include <math.h>

// GAT forward: N=100000, E=1.6M (row sorted = dest), F_IN=128, F_OUT=32,
// HEADS=8, ALPHA=0.2. Output [N, 256] f32.
//
// Round 14 (plane-partitioned scatter for XCD L2 affinity):
//  - featb re-laid as 4 head-pair planes [4][N][64] bf16 (12.8 MB each).
//  - scatter: plane = (blockIdx>>1)&3 -> each XCD pair touches ONE plane
//    (per-XCD compulsory L2 fills 51.2 -> 12.8 MB; total ~410 -> ~102 MB).
//    Wave = 4 edge-slots x 16 lanes: 4 edges x one 128B line per step,
//    per-edge VALU ~3.5x lower. Numerics identical to R11/R13.
//  - gemm: store addressing remapped to planes (static). prep/aproj
//    byte-identical to R13.

#define F_IN   128
#define F_ALL  256   // HEADS * F_OUT
#define HEADS  8
#define F_OUT  32
#define ALPHA  0.2f

using f32x4  = __attribute__((ext_vector_type(4))) float;
using bf16x8 = __attribute__((ext_vector_type(8))) short;
using u16x8  = __attribute__((ext_vector_type(8))) unsigned short;

static __device__ __forceinline__ unsigned short f32_to_bf16(float f) {
  union { float f; unsigned u; } v; v.f = f;
  unsigned r = v.u + 0x7FFF + ((v.u >> 16) & 1);   // RNE
  return (unsigned short)(r >> 16);
}
static __device__ __forceinline__ unsigned cvt_pk_bf16(float lo, float hi) {
  unsigned r;
  asm("v_cvt_pk_bf16_f32 %0, %1, %2" : "=v"(r) : "v"(lo), "v"(hi));
  return r;
}
static __device__ __forceinline__ float bf16_lo(unsigned d) {
  return __uint_as_float(d << 16);
}
static __device__ __forceinline__ float bf16_hi(unsigned d) {
  return __uint_as_float(d & 0xffff0000u);
}

// ---- 0) prep: x->bf16, kern->Wt bf16, ws/wn = W@att (f32), CSR ptr ----
__global__ __launch_bounds__(256) void prep(const float* __restrict__ x,
                                            const float* __restrict__ kern,
                                            const float* __restrict__ att_s,
                                            const float* __restrict__ att_n,
                                            const int* __restrict__ row,
                                            unsigned short* __restrict__ xb,
                                            unsigned short* __restrict__ Wt,
                                            float* __restrict__ ws,
                                            float* __restrict__ wn,
                                            int* __restrict__ ptr,
                                            int total_x8, int N, int E) {
  int id = blockIdx.x * 256 + threadIdx.x;
  if (id < total_x8) {
    const float4* x4 = reinterpret_cast<const float4*>(x);
    float4 v0 = x4[(size_t)id * 2], v1 = x4[(size_t)id * 2 + 1];
    u16x8 o;
    o[0] = f32_to_bf16(v0.x); o[1] = f32_to_bf16(v0.y);
    o[2] = f32_to_bf16(v0.z); o[3] = f32_to_bf16(v0.w);
    o[4] = f32_to_bf16(v1.x); o[5] = f32_to_bf16(v1.y);
    o[6] = f32_to_bf16(v1.z); o[7] = f32_to_bf16(v1.w);
    *reinterpret_cast<u16x8*>(xb + (size_t)id * 8) = o;
  }
  if (id < F_ALL * F_IN) {          // Wt[c][k] = kern[c>>5][k][c&31]
    int c = id >> 7, k = id & 127;
    Wt[id] = f32_to_bf16(kern[(size_t)(c >> 5) * (F_IN * F_OUT) + k * F_OUT + (c & 31)]);
  }
  if (id < 2 * HEADS * F_IN) {      // ws[h][k], wn[h][k] (f32, exact)
    int which = id >> 10;
    int hk = id & 1023;
    int h = hk >> 7, k = hk & 127;
    const float* att = which ? att_n : att_s;
    float s = 0.f;
#pragma unroll
    for (int f = 0; f < F_OUT; ++f)
      s += kern[(size_t)h * (F_IN * F_OUT) + k * F_OUT + f] * att[h * F_OUT + f];
    (which ? wn : ws)[hk] = s;
  }
  if (id <= N) {                    // CSR offsets via binary search
    int lo = 0, hi = E;
    while (lo < hi) {
      int mid = (lo + hi) >> 1;
      if (row[mid] < id) lo = mid + 1; else hi = mid;
    }
    ptr[id] = lo;
  }
}

// ---- 1) fused: [0,GB): feat = xb@Wt^T via MFMA (plane-major store);
//                [GB,..): a_s/a_n = x@ws/wn (exact f32) ----
__global__ __launch_bounds__(256) void gemm_aproj(
    const unsigned short* __restrict__ xb,   // [N][128] bf16
    const unsigned short* __restrict__ Wt,   // [256][128] bf16
    const float* __restrict__ x,             // [N][128] f32
    const float* __restrict__ ws, const float* __restrict__ wn,
    unsigned short* __restrict__ featb,      // [4][N][64] bf16 planes
    float* __restrict__ a_s, float* __restrict__ a_n,
    int N, int gemm_blocks, int aproj_waves) {
  const int t = threadIdx.x;

  if ((int)blockIdx.x < gemm_blocks) {
    const int w  = t >> 6;        // wave 0..3
    const int l  = t & 63;
    const int lr = l & 15;        // node within 16-tile (D col)
    const int lq = l >> 4;        // k-slice / D row group
    const int n0 = blockIdx.x * 64 + w * 16;

    f32x4 acc[16];
#pragma unroll
    for (int ct = 0; ct < 16; ++ct) acc[ct] = (f32x4){0.f, 0.f, 0.f, 0.f};

    int ar = n0 + lr; if (ar >= N) ar = N - 1;
    const unsigned short* xrow = xb + (size_t)ar * F_IN + lq * 8;
    bf16x8 xfr[4];
#pragma unroll
    for (int kc = 0; kc < 4; ++kc)
      xfr[kc] = *reinterpret_cast<const bf16x8*>(xrow + kc * 32);

#pragma unroll
    for (int ct = 0; ct < 16; ++ct) {
      const unsigned short* wrow = Wt + (size_t)(ct * 16 + lr) * F_IN + lq * 8;
#pragma unroll
      for (int kc = 0; kc < 4; ++kc) {
        bf16x8 wfr = *reinterpret_cast<const bf16x8*>(wrow + kc * 32);
        acc[ct] = __builtin_amdgcn_mfma_f32_16x16x32_bf16(wfr, xfr[kc], acc[ct], 0, 0, 0);
      }
    }
    // lane owns node ar; col = ct*16 + lq*4 + r -> plane ct>>2,
    // within-plane col cp = (ct&3)*16 + lq*4 : packed dwordx2 stores
    if (n0 + lr < N) {
#pragma unroll
      for (int ct = 0; ct < 16; ++ct) {
        unsigned short* dst = featb + ((size_t)(ct >> 2) * N + ar) * 64
                              + (ct & 3) * 16 + lq * 4;
        uint2 v;
        v.x = cvt_pk_bf16(acc[ct][0], acc[ct][1]);
        v.y = cvt_pk_bf16(acc[ct][2], acc[ct][3]);
        *reinterpret_cast<uint2*>(dst) = v;
      }
    }
    return;
  }

  // ---------- a_proj: exact f32 logits, wave per node ----------
  const int l = t & 63;
  const int o = l & 15, q = l >> 4;
  const int wid = (((int)blockIdx.x - gemm_blocks) * 256 + t) >> 6;

  const float* wrow = (o < 8 ? ws + o * F_IN : wn + (o - 8) * F_IN) + q * 32;
  float4 wv[8];
#pragma unroll
  for (int i = 0; i < 8; i++) wv[i] = reinterpret_cast<const float4*>(wrow)[i];

  for (int n = wid; n < N; n += aproj_waves) {
    const float4* xr = reinterpret_cast<const float4*>(x + (size_t)n * F_IN + q * 32);
    float acc = 0.f;
#pragma unroll
    for (int i = 0; i < 8; i++) {
      float4 xv = xr[i];
      acc += xv.x * wv[i].x + xv.y * wv[i].y + xv.z * wv[i].z + xv.w * wv[i].w;
    }
    acc += __shfl_xor(acc, 16);
    acc += __shfl_xor(acc, 32);
    if (l < 16) {
      if (o < 8) a_s[n * HEADS + o] = acc;
      else       a_n[n * HEADS + (o - 8)] = acc;
    }
  }
}

// ---- 2) scatter: wave/node/plane; 4 edge-slots x 16 lanes.
// plane = (blockIdx>>1)&3 -> XCD-pair affine under %8 round-robin. ----
__global__ __launch_bounds__(256) void gat_scatter(
    const unsigned short* __restrict__ featb,  // [4][N][64] planes
    const float* __restrict__ a_s, const float* __restrict__ a_n,
    const int* __restrict__ col, const int* __restrict__ ptr,
    const float* __restrict__ biases, float* __restrict__ out, int N) {
  const int b  = blockIdx.x;
  const int p  = (b >> 1) & 3;                // plane (heads 2p, 2p+1)
  const int ng = (b >> 3) * 2 + (b & 1);      // node group
  const int t  = threadIdx.x;
  const int n  = ng * 4 + (t >> 6);           // wave per node
  if (n >= N) return;
  const int l  = t & 63;
  const int es = l >> 4;                      // edge slot 0..3
  const int q  = l & 15;                      // dword-pair in 128B line
  const int h  = 2 * p + (q >> 3);            // head
  const int ob = p * 64 + q * 4;              // output feature base

  const int start = ptr[n];
  const int deg   = ptr[n + 1] - start;

  if (deg == 0) {
    if (l < 16)
      *reinterpret_cast<float4*>(&out[(size_t)n * F_ALL + ob]) =
          *reinterpret_cast<const float4*>(&biases[ob]);
    return;
  }

  const float as = a_s[n * HEADS + h];
  const unsigned* fpl = reinterpret_cast<const unsigned*>(featb) + (size_t)p * N * 32;

  float a0 = 0.f, a1 = 0.f, a2 = 0.f, a3 = 0.f, smp = 0.f;

  for (int cs = 0; cs < deg; cs += 32) {
    const int le = l & 31;
    int creg = (cs + le < deg) ? col[start + cs + le] : 0;
    const int wl = (deg - cs) < 32 ? (deg - cs) : 32;
#pragma unroll 2
    for (int e0 = 0; e0 < wl; e0 += 4) {
      int ei = e0 + es;
      int c  = __shfl(creg, ei, 32);
      if (ei < wl) {
        float v = as + a_n[c * HEADS + h];
        v = v > 0.f ? v : ALPHA * v;
        float w = __expf(v);
        smp += w;
        uint2 d = *reinterpret_cast<const uint2*>(fpl + (size_t)c * 32 + q * 2);
        a0 = fmaf(w, bf16_lo(d.x), a0);
        a1 = fmaf(w, bf16_hi(d.x), a1);
        a2 = fmaf(w, bf16_lo(d.y), a2);
        a3 = fmaf(w, bf16_hi(d.y), a3);
      }
    }
  }

  // reduce over the es axis (lanes l, l^16, l^32 share (q,h))
  a0 += __shfl_xor(a0, 16); a0 += __shfl_xor(a0, 32);
  a1 += __shfl_xor(a1, 16); a1 += __shfl_xor(a1, 32);
  a2 += __shfl_xor(a2, 16); a2 += __shfl_xor(a2, 32);
  a3 += __shfl_xor(a3, 16); a3 += __shfl_xor(a3, 32);
  smp += __shfl_xor(smp, 16); smp += __shfl_xor(smp, 32);

  if (l < 16) {
    const float inv = 1.0f / smp;
    const float4 bv = *reinterpret_cast<const float4*>(&biases[ob]);
    float4 o = {a0 * inv + bv.x, a1 * inv + bv.y, a2 * inv + bv.z, a3 * inv + bv.w};
    *reinterpret_cast<float4*>(&out[(size_t)n * F_ALL + ob]) = o;
  }
}

extern "C" void kernel_launch(void* const* d_in, const int* in_sizes, int n_in,
                              void* d_out, int out_size, void* d_ws, size_t ws_size,
                              hipStream_t stream) {
  const float* x      = (const float*)d_in[0];
  const int*   row    = (const int*)d_in[1];
  const int*   col    = (const int*)d_in[2];
  const float* kern   = (const float*)d_in[3];
  const float* att_s  = (const float*)d_in[4];
  const float* att_n  = (const float*)d_in[5];
  const float* biases = (const float*)d_in[6];

  const int N = in_sizes[0] / F_IN;   // 100000
  const int E = in_sizes[1];          // 1600000

  // workspace: featb | xb | Wt | ws | wn | a_s | a_n | ptr   (~84 MB)
  unsigned short* featb = (unsigned short*)d_ws;
  unsigned short* xb    = featb + (size_t)N * F_ALL;
  unsigned short* Wt    = xb + (size_t)N * F_IN;
  float* ws  = (float*)(Wt + F_ALL * F_IN);
  float* wn  = ws + HEADS * F_IN;
  float* a_s = wn + HEADS * F_IN;
  float* a_n = a_s + (size_t)N * HEADS;
  int*   ptr = (int*)(a_n + (size_t)N * HEADS);
  float* out = (float*)d_out;

  const int total_x8     = N * F_IN / 8;   // 1.6M ids
  const int gemm_blocks  = (N + 63) / 64;
  const int aproj_blocks = 1024;
  const int aproj_waves  = aproj_blocks * 4;

  // scatter grid: 8 blocks per (2 node-groups x 4 planes) stride
  const int ngroups   = (N + 3) / 4;
  const int ngpad     = (ngroups + 1) & ~1;
  const int scat_blocks = ngpad * 4;

  hipLaunchKernelGGL(prep, dim3((total_x8 + 255) / 256), dim3(256), 0, stream,
                     x, kern, att_s, att_n, row, xb, Wt, ws, wn, ptr, total_x8, N, E);
  hipLaunchKernelGGL(gemm_aproj, dim3(gemm_blocks + aproj_blocks), dim3(256), 0, stream,
                     xb, Wt, x, ws, wn, featb, a_s, a_n, N, gemm_blocks, aproj_waves);
  hipLaunchKernelGGL(gat_scatter, dim3(scat_blocks), dim3(256), 0, stream,
                     featb, a_s, a_n, col, ptr, biases, out, N);
}

// Round 16
// 259.376 us; speedup vs baseline: 1.2700x; 1.2700x over previous
//
#include <hip/hip_runtime.h>
#include <hip/hip_bf16.h>
#include <math.h>

// GAT forward: N=100000, E=1.6M (row sorted = dest), F_IN=128, F_OUT=32,
// HEADS=8, ALPHA=0.2. Output [N, 256] f32.
//
// Round 16: R13 byte-for-byte (best passing, 260.8 us).
//  - R9/R15's in-reg-cvt GEMM abandoned: 2/2 flaky failures (first-call
//    absmax / graph-replay tripwire), mechanism unidentified after audit.
//  - scatter: R11 structure (150 us; 462 MB fetch = compulsory cross-XCD
//    fills at ~3.8 TB/s random-gather service; MLP/VALU/partition variants
//    all null or worse -> structural floor).
//  - front-end: prep (x->bf16 + Wt + ws/wn + CSR ptr) + fused gemm_aproj.

#define F_IN   128
#define F_ALL  256   // HEADS * F_OUT
#define HEADS  8
#define F_OUT  32
#define ALPHA  0.2f

using f32x4  = __attribute__((ext_vector_type(4))) float;
using bf16x8 = __attribute__((ext_vector_type(8))) short;
using u16x8  = __attribute__((ext_vector_type(8))) unsigned short;

static __device__ __forceinline__ unsigned short f32_to_bf16(float f) {
  union { float f; unsigned u; } v; v.f = f;
  unsigned r = v.u + 0x7FFF + ((v.u >> 16) & 1);   // RNE
  return (unsigned short)(r >> 16);
}
static __device__ __forceinline__ unsigned cvt_pk_bf16(float lo, float hi) {
  unsigned r;
  asm("v_cvt_pk_bf16_f32 %0, %1, %2" : "=v"(r) : "v"(lo), "v"(hi));
  return r;
}
static __device__ __forceinline__ float bf16_lo(unsigned d) {
  return __uint_as_float(d << 16);
}
static __device__ __forceinline__ float bf16_hi(unsigned d) {
  return __uint_as_float(d & 0xffff0000u);
}

// ---- 0) prep: x->bf16, kern->Wt bf16, ws/wn = W@att (f32), CSR ptr ----
__global__ __launch_bounds__(256) void prep(const float* __restrict__ x,
                                            const float* __restrict__ kern,
                                            const float* __restrict__ att_s,
                                            const float* __restrict__ att_n,
                                            const int* __restrict__ row,
                                            unsigned short* __restrict__ xb,
                                            unsigned short* __restrict__ Wt,
                                            float* __restrict__ ws,
                                            float* __restrict__ wn,
                                            int* __restrict__ ptr,
                                            int total_x8, int N, int E) {
  int id = blockIdx.x * 256 + threadIdx.x;
  if (id < total_x8) {
    const float4* x4 = reinterpret_cast<const float4*>(x);
    float4 v0 = x4[(size_t)id * 2], v1 = x4[(size_t)id * 2 + 1];
    u16x8 o;
    o[0] = f32_to_bf16(v0.x); o[1] = f32_to_bf16(v0.y);
    o[2] = f32_to_bf16(v0.z); o[3] = f32_to_bf16(v0.w);
    o[4] = f32_to_bf16(v1.x); o[5] = f32_to_bf16(v1.y);
    o[6] = f32_to_bf16(v1.z); o[7] = f32_to_bf16(v1.w);
    *reinterpret_cast<u16x8*>(xb + (size_t)id * 8) = o;
  }
  if (id < F_ALL * F_IN) {          // Wt[c][k] = kern[c>>5][k][c&31]
    int c = id >> 7, k = id & 127;
    Wt[id] = f32_to_bf16(kern[(size_t)(c >> 5) * (F_IN * F_OUT) + k * F_OUT + (c & 31)]);
  }
  if (id < 2 * HEADS * F_IN) {      // ws[h][k], wn[h][k] (f32, exact)
    int which = id >> 10;
    int hk = id & 1023;
    int h = hk >> 7, k = hk & 127;
    const float* att = which ? att_n : att_s;
    float s = 0.f;
#pragma unroll
    for (int f = 0; f < F_OUT; ++f)
      s += kern[(size_t)h * (F_IN * F_OUT) + k * F_OUT + f] * att[h * F_OUT + f];
    (which ? wn : ws)[hk] = s;
  }
  if (id <= N) {                    // CSR offsets via binary search
    int lo = 0, hi = E;
    while (lo < hi) {
      int mid = (lo + hi) >> 1;
      if (row[mid] < id) lo = mid + 1; else hi = mid;
    }
    ptr[id] = lo;
  }
}

// ---- 1) fused: [0,GB): feat = xb@Wt^T via MFMA ; [GB,..): a_s/a_n = x@ws/wn ----
__global__ __launch_bounds__(256) void gemm_aproj(
    const unsigned short* __restrict__ xb,   // [N][128] bf16
    const unsigned short* __restrict__ Wt,   // [256][128] bf16
    const float* __restrict__ x,             // [N][128] f32
    const float* __restrict__ ws, const float* __restrict__ wn,
    unsigned short* __restrict__ featb,      // [N][256] bf16
    float* __restrict__ a_s, float* __restrict__ a_n,
    int N, int gemm_blocks, int aproj_waves) {
  const int t = threadIdx.x;

  if ((int)blockIdx.x < gemm_blocks) {
    // ---------- GEMM: D[wcol][node] = mfma(W, x) ----------
    const int w  = t >> 6;        // wave 0..3
    const int l  = t & 63;
    const int lr = l & 15;        // node within 16-tile (D col)
    const int lq = l >> 4;        // k-slice / D row group
    const int n0 = blockIdx.x * 64 + w * 16;

    f32x4 acc[16];
#pragma unroll
    for (int ct = 0; ct < 16; ++ct) acc[ct] = (f32x4){0.f, 0.f, 0.f, 0.f};

    int ar = n0 + lr; if (ar >= N) ar = N - 1;
    const unsigned short* xrow = xb + (size_t)ar * F_IN + lq * 8;
    bf16x8 xfr[4];
#pragma unroll
    for (int kc = 0; kc < 4; ++kc)
      xfr[kc] = *reinterpret_cast<const bf16x8*>(xrow + kc * 32);

#pragma unroll
    for (int ct = 0; ct < 16; ++ct) {
      const unsigned short* wrow = Wt + (size_t)(ct * 16 + lr) * F_IN + lq * 8;
#pragma unroll
      for (int kc = 0; kc < 4; ++kc) {
        bf16x8 wfr = *reinterpret_cast<const bf16x8*>(wrow + kc * 32);
        acc[ct] = __builtin_amdgcn_mfma_f32_16x16x32_bf16(wfr, xfr[kc], acc[ct], 0, 0, 0);
      }
    }
    // lane owns node ar, cols ct*16 + lq*4 + r: packed dwordx2 stores
    if (n0 + lr < N) {
      unsigned short* frow = featb + (size_t)ar * F_ALL + lq * 4;
#pragma unroll
      for (int ct = 0; ct < 16; ++ct) {
        uint2 v;
        v.x = cvt_pk_bf16(acc[ct][0], acc[ct][1]);
        v.y = cvt_pk_bf16(acc[ct][2], acc[ct][3]);
        *reinterpret_cast<uint2*>(frow + ct * 16) = v;
      }
    }
    return;
  }

  // ---------- a_proj: exact f32 logits, wave per node ----------
  const int l = t & 63;
  const int o = l & 15, q = l >> 4;
  const int wid = (((int)blockIdx.x - gemm_blocks) * 256 + t) >> 6;

  const float* wrow = (o < 8 ? ws + o * F_IN : wn + (o - 8) * F_IN) + q * 32;
  float4 wv[8];
#pragma unroll
  for (int i = 0; i < 8; i++) wv[i] = reinterpret_cast<const float4*>(wrow)[i];

  for (int n = wid; n < N; n += aproj_waves) {
    const float4* xr = reinterpret_cast<const float4*>(x + (size_t)n * F_IN + q * 32);
    float acc = 0.f;
#pragma unroll
    for (int i = 0; i < 8; i++) {
      float4 xv = xr[i];
      acc += xv.x * wv[i].x + xv.y * wv[i].y + xv.z * wv[i].z + xv.w * wv[i].w;
    }
    acc += __shfl_xor(acc, 16);
    acc += __shfl_xor(acc, 32);
    if (l < 16) {
      if (o < 8) a_s[n * HEADS + o] = acc;
      else       a_n[n * HEADS + (o - 8)] = acc;
    }
  }
}

// ---- 2) per-node softmax + SpMM: ONE wave per node, single fused pass ----
// 4 groups x 16 lanes; group j owns line j (heads 2j, 2j+1).
__global__ __launch_bounds__(256) void gat_scatter(
    const unsigned short* __restrict__ featb,
    const float* __restrict__ a_s, const float* __restrict__ a_n,
    const int* __restrict__ col, const int* __restrict__ ptr,
    const float* __restrict__ biases, float* __restrict__ out, int N) {
  const int t  = threadIdx.x;
  const int n  = blockIdx.x * 4 + (t >> 6);   // 4 nodes per block, wave/node
  if (n >= N) return;
  const int l  = t & 63;
  const int j  = l >> 4;                      // line group 0..3
  const int q  = l & 15;                      // lane within group
  const int h0 = 2 * j + (q >> 3);            // this lane's head
  const int obase = j * 64 + q * 4;           // 4 output features
  const size_t dbase = (size_t)j * 32 + q * 2; // dword offset in feat row

  const int start = ptr[n];
  const int deg   = ptr[n + 1] - start;

  const float4 bv = *reinterpret_cast<const float4*>(&biases[obase]);
  if (deg == 0) {
    *reinterpret_cast<float4*>(&out[(size_t)n * F_ALL + obase]) = bv;
    return;
  }

  const float as = a_s[n * HEADS + h0];
  const unsigned* fu32 = reinterpret_cast<const unsigned*>(featb);

  float a0 = 0.f, a1 = 0.f, a2 = 0.f, a3 = 0.f, sm = 0.f;

  if (deg <= 32) {
    // preload col into lanes 0..31 (lanes 32-63 mirror for width-32 shfl)
    const int le = l & 31;
    int creg = (le < deg) ? col[start + le] : 0;
#pragma unroll 4
    for (int e = 0; e < deg; ++e) {
      int c = __shfl(creg, e, 32);
      float an = a_n[c * HEADS + h0];
      float v = as + an;
      v = v > 0.f ? v : ALPHA * v;
      float w = __expf(v);
      sm += w;
      uint2 d = *reinterpret_cast<const uint2*>(fu32 + (size_t)c * 128 + dbase);
      a0 = fmaf(w, bf16_lo(d.x), a0);
      a1 = fmaf(w, bf16_hi(d.x), a1);
      a2 = fmaf(w, bf16_lo(d.y), a2);
      a3 = fmaf(w, bf16_hi(d.y), a3);
    }
  } else {
    // rare deg>32: same body, col loaded per edge (uniform broadcast)
    for (int e = 0; e < deg; ++e) {
      int c = col[start + e];
      float an = a_n[c * HEADS + h0];
      float v = as + an;
      v = v > 0.f ? v : ALPHA * v;
      float w = __expf(v);
      sm += w;
      uint2 d = *reinterpret_cast<const uint2*>(fu32 + (size_t)c * 128 + dbase);
      a0 = fmaf(w, bf16_lo(d.x), a0);
      a1 = fmaf(w, bf16_hi(d.x), a1);
      a2 = fmaf(w, bf16_lo(d.y), a2);
      a3 = fmaf(w, bf16_hi(d.y), a3);
    }
  }

  const float inv = 1.0f / sm;
  float4 o = {a0 * inv + bv.x, a1 * inv + bv.y, a2 * inv + bv.z, a3 * inv + bv.w};
  *reinterpret_cast<float4*>(&out[(size_t)n * F_ALL + obase]) = o;
}

extern "C" void kernel_launch(void* const* d_in, const int* in_sizes, int n_in,
                              void* d_out, int out_size, void* d_ws, size_t ws_size,
                              hipStream_t stream) {
  const float* x      = (const float*)d_in[0];
  const int*   row    = (const int*)d_in[1];
  const int*   col    = (const int*)d_in[2];
  const float* kern   = (const float*)d_in[3];
  const float* att_s  = (const float*)d_in[4];
  const float* att_n  = (const float*)d_in[5];
  const float* biases = (const float*)d_in[6];

  const int N = in_sizes[0] / F_IN;   // 100000
  const int E = in_sizes[1];          // 1600000

  // workspace: featb | xb | Wt | ws | wn | a_s | a_n | ptr   (~84 MB)
  unsigned short* featb = (unsigned short*)d_ws;
  unsigned short* xb    = featb + (size_t)N * F_ALL;
  unsigned short* Wt    = xb + (size_t)N * F_IN;
  float* ws  = (float*)(Wt + F_ALL * F_IN);
  float* wn  = ws + HEADS * F_IN;
  float* a_s = wn + HEADS * F_IN;
  float* a_n = a_s + (size_t)N * HEADS;
  int*   ptr = (int*)(a_n + (size_t)N * HEADS);
  float* out = (float*)d_out;

  const int total_x8     = N * F_IN / 8;   // 1.6M ids
  const int gemm_blocks  = (N + 63) / 64;
  const int aproj_blocks = 1024;
  const int aproj_waves  = aproj_blocks * 4;

  hipLaunchKernelGGL(prep, dim3((total_x8 + 255) / 256), dim3(256), 0, stream,
                     x, kern, att_s, att_n, row, xb, Wt, ws, wn, ptr, total_x8, N, E);
  hipLaunchKernelGGL(gemm_aproj, dim3(gemm_blocks + aproj_blocks), dim3(256), 0, stream,
                     xb, Wt, x, ws, wn, featb, a_s, a_n, N, gemm_blocks, aproj_waves);
  hipLaunchKernelGGL(gat_scatter, dim3((N + 3) / 4), dim3(256), 0, stream,
                     featb, a_s, a_n, col, ptr, biases, out, N);
}